// Round 3
// baseline (72.633 us; speedup 1.0000x reference)
//
#include <hip/hip_runtime.h>
#include <hip/hip_bf16.h>

// x: [4, 4096, 4096] f32, W1: [48, 4096] f32, W2: [48, 48] f32
// out: [4, 4, 4096, 12] f32  (C, B, T, L/C)
#define DDIM 4096
#define LTOT 48

typedef __attribute__((ext_vector_type(4))) float f32x4;
typedef __attribute__((ext_vector_type(8))) short bf16x8;

__device__ __forceinline__ void gload_lds16(const void* g, void* l) {
    __builtin_amdgcn_global_load_lds(
        (const __attribute__((address_space(1))) void*)g,
        (__attribute__((address_space(3))) void*)l, 16, 0, 0);
}

__device__ __forceinline__ unsigned cvt_pk(float x, float y) {
    union { __hip_bfloat162 h; unsigned u; } c;
    c.h = __float22bfloat162_rn(make_float2(x, y));
    return c.u;
}

// ---- kernel 0: W1 fp32 -> bf16 (RNE) into workspace ----
__global__ void w1cvt_kernel(const float* __restrict__ w1, ushort* __restrict__ w1b) {
    int i = blockIdx.x * 256 + threadIdx.x;
    union { float f; unsigned u; } v; v.f = w1[i];
    unsigned r = v.u + 0x7fffu + ((v.u >> 16) & 1u);
    w1b[i] = (ushort)(r >> 16);
}

// ---- fused: one wave per block, 16 rows, full-K streaming in 1KB bursts ----
__global__ __launch_bounds__(64, 1) void fused_kernel(
        const float* __restrict__ x,
        const ushort* __restrict__ w1b,
        const float* __restrict__ w2,
        float* __restrict__ out) {
    // 2 buffers x 16KB: buffer = 16 rows x 256 floats, 16B-blocks XOR-swizzled
    __shared__ __align__(1024) char smem[32768];

    const int lane = threadIdx.x;       // 0..63
    const int rl   = lane & 15;         // A-row / B-row / C-col
    const int kg   = lane >> 4;         // k-group 0..3
    const int row0 = blockIdx.x * 16;

    // stage chunk c (K range c*256..+255 of all 16 rows) into buffer c&1.
    // One instruction = one row's contiguous 1KB (lanes permuted within 256B
    // groups = inverse of the read-side swizzle; linear LDS dest).
    auto stage = [&](int c) {
        char* lb = smem + (c & 1) * 16384;
        const float* xb = x + (size_t)row0 * DDIM + c * 256;
        #pragma unroll
        for (int r = 0; r < 16; ++r) {
            int sblk = (lane & 48) | ((lane ^ r) & 15);
            gload_lds16(xb + (size_t)r * DDIM + sblk * 4, lb + r * 1024);
        }
    };

    // B fragments for MFMA step s (K=64): 6 x 16B from L2-resident W1b
    auto loadB = [&](int s, bf16x8 (&bf)[6]) {
        const ushort* bp = w1b + (size_t)rl * DDIM + s * 64 + kg * 8;
        #pragma unroll
        for (int n = 0; n < 3; ++n)
            #pragma unroll
            for (int h = 0; h < 2; ++h)
                bf[n * 2 + h] = *(const bf16x8*)(bp + n * 16 * DDIM + h * 32);
    };

    bf16x8 breg[2][6];
    f32x4 acc[3] = {{0.f,0.f,0.f,0.f},{0.f,0.f,0.f,0.f},{0.f,0.f,0.f,0.f}};
    float ss = 0.f;

    loadB(0, breg[0]);
    stage(0);

    #pragma unroll
    for (int c = 0; c < 16; ++c) {
        // stage(c) complete: newer vmem = the 24 B-loads of the previous body
        if (c == 0) asm volatile("s_waitcnt vmcnt(0)" ::: "memory");
        else        asm volatile("s_waitcnt vmcnt(24)" ::: "memory");

        const char* lb = smem + (c & 1) * 16384;
        f32x4 a[4][2][2];
        #pragma unroll
        for (int t = 0; t < 4; ++t)
            #pragma unroll
            for (int h = 0; h < 2; ++h)
                #pragma unroll
                for (int p = 0; p < 2; ++p) {
                    int g   = t * 16 + h * 8 + kg * 2 + p;
                    int pos = (g & 48) | ((g ^ rl) & 15);
                    a[t][h][p] = *(const f32x4*)(lb + rl * 1024 + pos * 16);
                }
        // a[] ready; also orders these ds_reads before next stage's DMA writes
        asm volatile("s_waitcnt lgkmcnt(0)" ::: "memory");
        __builtin_amdgcn_sched_barrier(0);
        if (c < 15) stage(c + 1);
        __builtin_amdgcn_sched_barrier(0);
        asm volatile("" ::: "memory");   // pin B-loads after the stage bundle

        #pragma unroll
        for (int t = 0; t < 4; ++t) {
            const int s = c * 4 + t;
            if (s + 1 < 64) loadB(s + 1, breg[(s + 1) & 1]);
            #pragma unroll
            for (int h = 0; h < 2; ++h) {
                f32x4 a0 = a[t][h][0], a1 = a[t][h][1];
                ss = fmaf(a0.x, a0.x, ss); ss = fmaf(a0.y, a0.y, ss);
                ss = fmaf(a0.z, a0.z, ss); ss = fmaf(a0.w, a0.w, ss);
                ss = fmaf(a1.x, a1.x, ss); ss = fmaf(a1.y, a1.y, ss);
                ss = fmaf(a1.z, a1.z, ss); ss = fmaf(a1.w, a1.w, ss);
                union { bf16x8 v; unsigned u[4]; } af;
                af.u[0] = cvt_pk(a0.x, a0.y); af.u[1] = cvt_pk(a0.z, a0.w);
                af.u[2] = cvt_pk(a1.x, a1.y); af.u[3] = cvt_pk(a1.z, a1.w);
                #pragma unroll
                for (int n = 0; n < 3; ++n)
                    acc[n] = __builtin_amdgcn_mfma_f32_16x16x32_bf16(
                                 af.v, breg[s & 1][n * 2 + h], acc[n], 0, 0, 0);
            }
        }
    }

    asm volatile("s_waitcnt vmcnt(0) lgkmcnt(0)" ::: "memory");

    // ---- wave-private epilogue (no cross-wave sync needed) ----
    ss += __shfl_xor(ss, 16);
    ss += __shfl_xor(ss, 32);
    const float scl = rsqrtf(ss * (1.0f / (float)DDIM) + 1e-5f);  // row rl's scale

    float* dots = (float*)smem;             // [16][48]
    float* gbuf = (float*)(smem + 3072);    // [16][48]
    float* w2s  = (float*)(smem + 6144);    // [48][48]

    #pragma unroll
    for (int n = 0; n < 3; ++n)
        #pragma unroll
        for (int i = 0; i < 4; ++i)
            dots[(kg * 4 + i) * 48 + n * 16 + rl] = acc[n][i];

    #pragma unroll
    for (int i = 0; i < 9; ++i) {
        int v = lane + i * 64;              // 576 f32x4 = 48*48 floats
        f32x4 w = *(const f32x4*)(w2 + v * 4);
        *(f32x4*)(w2s + v * 4) = w;
    }
    asm volatile("s_waitcnt lgkmcnt(0)" ::: "memory");

    // gelu for row rl, cols kg*12..+11
    #pragma unroll
    for (int j = 0; j < 12; ++j) {
        float h = dots[rl * 48 + kg * 12 + j] * scl;
        gbuf[rl * 48 + kg * 12 + j] = h * 0.5f * (1.0f + erff(h * 0.70710678118654752f));
    }
    asm volatile("s_waitcnt lgkmcnt(0)" ::: "memory");

    f32x4 grow[12];
    #pragma unroll
    for (int q = 0; q < 12; ++q)
        grow[q] = *(const f32x4*)(gbuf + rl * 48 + q * 4);

    float o[12];
    #pragma unroll
    for (int jj = 0; jj < 12; ++jj) {
        const int l = kg * 12 + jj;
        float sacc = 0.f;
        #pragma unroll
        for (int q = 0; q < 12; ++q) {
            f32x4 wv = *(const f32x4*)(w2s + l * 48 + q * 4);
            sacc = fmaf(grow[q].x, wv.x, sacc);
            sacc = fmaf(grow[q].y, wv.y, sacc);
            sacc = fmaf(grow[q].z, wv.z, sacc);
            sacc = fmaf(grow[q].w, wv.w, sacc);
        }
        o[jj] = sacc;
    }

    const int rg = row0 + rl;
    const int b  = rg >> 12;
    const int t  = rg & 4095;
    float* op = out + ((size_t)(kg * 4 + b) * 4096 + t) * 12;
    *(f32x4*)(op + 0) = {o[0], o[1], o[2],  o[3]};
    *(f32x4*)(op + 4) = {o[4], o[5], o[6],  o[7]};
    *(f32x4*)(op + 8) = {o[8], o[9], o[10], o[11]};
}

extern "C" void kernel_launch(void* const* d_in, const int* in_sizes, int n_in,
                              void* d_out, int out_size, void* d_ws, size_t ws_size,
                              hipStream_t stream) {
    const float* x  = (const float*)d_in[0];
    const float* W1 = (const float*)d_in[1];
    const float* W2 = (const float*)d_in[2];
    float* out = (float*)d_out;
    ushort* w1b = (ushort*)d_ws;

    w1cvt_kernel<<<(LTOT * DDIM) / 256, 256, 0, stream>>>(W1, w1b);
    fused_kernel<<<16384 / 16, 64, 0, stream>>>(x, w1b, W2, out);
}